// Round 4
// baseline (335.133 us; speedup 1.0000x reference)
//
#include <hip/hip_runtime.h>
#include <stdint.h>

typedef unsigned short u16;
typedef __bf16  bf16x8 __attribute__((ext_vector_type(8)));
typedef float   f32x4  __attribute__((ext_vector_type(4)));

__device__ __forceinline__ u16 f2bf(float f) {
    union { float f; unsigned u; } c; c.f = f;
    unsigned r = c.u + 0x7fffu + ((c.u >> 16) & 1u);   // RNE, finite inputs
    return (u16)(r >> 16);
}
__device__ __forceinline__ float bf2f(u16 b) {
    union { unsigned u; float f; } c; c.u = ((unsigned)b) << 16; return c.f;
}

// async 16B global->LDS. Generic LDS ptr: low 32 bits are the LDS offset on gfx9+.
__device__ __forceinline__ void g2l16(const u16* g, u16* l) {
    __builtin_amdgcn_global_load_lds(
        (__attribute__((address_space(1))) void*)(uintptr_t)g,
        (__attribute__((address_space(3))) void*)(uint32_t)(uintptr_t)l,
        16, 0, 0);
}

// ---------------------------------------------------------------------------
// NT GEMM (bf16 in, fp32 acc): C[m,n] = sum_k A[m,k]*B[n,k] (+ bias[m]).
// A,B row-major bf16, ld == K. Output bf16 or fp32 per OUT_F32.
// Tile TM x 128, BK=64, 256 threads = 4 waves (2x2); wave covers (TM/2) x 64.
// TM=128 for big GEMMs (best stage:MFMA ratio); TM=64 for small grids (2x
// blocks -> more resident blocks/CU to absorb barrier drains).
// LDS XOR-swizzle: physical 16B chunk = logical ^ (row&7) -> 2-way (free)
// bank aliasing on ds_read_b128. M mult of TM; N mult of 128; K mult of 64.
// ---------------------------------------------------------------------------
template <int TM, bool HAS_BIAS, bool OUT_F32>
__global__ __launch_bounds__(256) void gemm_nt(
    const u16* __restrict__ A, const u16* __restrict__ B, void* __restrict__ C,
    const float* __restrict__ bias, int M, int N, int K,
    long sA, long sB, long sC)
{
    constexpr int MI = TM / 32;          // mi-tiles per wave
    constexpr int NA = TM / 32;          // A staging 16B-slots per thread
    __shared__ __align__(16) u16 As[TM * 64];
    __shared__ __align__(16) u16 Bs[128 * 64];

    const int bz = blockIdx.z;
    const int m0 = blockIdx.y * TM;
    const int n0 = blockIdx.x * 128;
    const u16* Ab = A + (long)bz * sA;
    const u16* Bb = B + (long)bz * sB;

    const int t = threadIdx.x;
    const int w = t >> 6, lane = t & 63;
    const int wr = w >> 1, wc = w & 1;

    f32x4 acc[MI][4];
    const f32x4 zero = {0.f, 0.f, 0.f, 0.f};
#pragma unroll
    for (int i = 0; i < MI; ++i)
#pragma unroll
        for (int j = 0; j < 4; ++j) acc[i][j] = zero;

    // Staging: 16B-slot s covers LDS [row][phys_chunk]; the global source
    // column is swizzled so phys = logical ^ (row&7).
    int  aslot[NA]; long aoff[NA];
#pragma unroll
    for (int i = 0; i < NA; ++i) {
        const int s   = i * 256 + t;
        const int row = s >> 3;
        const int col = ((s & 7) ^ (row & 7)) * 8;
        aslot[i] = s * 8;
        aoff[i]  = (long)(m0 + row) * K + col;
    }
    int  bslot[4]; long boff[4];
#pragma unroll
    for (int i = 0; i < 4; ++i) {
        const int s   = i * 256 + t;
        const int row = s >> 3;
        const int col = ((s & 7) ^ (row & 7)) * 8;
        bslot[i] = s * 8;
        boff[i]  = (long)(n0 + row) * K + col;
    }

    // Fragment read offsets (swizzled): lane reads logical chunk (kh*4+q) of
    // row fr -> physical chunk ((kh*4+q) ^ (fr&7)).
    const int fr = lane & 15;
    const int q  = lane >> 4;
    const int o0 = ((q ^ (fr & 7)) * 8);   // kh=0; kh=1 is o0 ^ 32
    const u16* fa = &As[(wr * (TM / 2) + fr) * 64];
    const u16* fb = &Bs[(wc * 64 + fr) * 64];

    for (int k0 = 0; k0 < K; k0 += 64) {
#pragma unroll
        for (int i = 0; i < NA; ++i) g2l16(Ab + aoff[i] + k0, &As[aslot[i]]);
#pragma unroll
        for (int i = 0; i < 4; ++i)  g2l16(Bb + boff[i] + k0, &Bs[bslot[i]]);
        __syncthreads();   // drains vmcnt before barrier

#pragma unroll
        for (int kh = 0; kh < 2; ++kh) {
            const int o = o0 ^ (kh * 32);
            bf16x8 af[MI], bv[4];
#pragma unroll
            for (int mi = 0; mi < MI; ++mi) af[mi] = *(const bf16x8*)(fa + mi * 1024 + o);
#pragma unroll
            for (int ni = 0; ni < 4; ++ni)  bv[ni] = *(const bf16x8*)(fb + ni * 1024 + o);
#pragma unroll
            for (int mi = 0; mi < MI; ++mi)
#pragma unroll
                for (int ni = 0; ni < 4; ++ni)
                    acc[mi][ni] = __builtin_amdgcn_mfma_f32_16x16x32_bf16(
                        af[mi], bv[ni], acc[mi][ni], 0, 0, 0);
        }
        __syncthreads();
    }

    // C/D layout (m89-verified): col = lane&15, row = (lane>>4)*4 + reg
    const int ccol  = n0 + wc * 64 + fr;
    const int crow0 = m0 + wr * (TM / 2) + (lane >> 4) * 4;
#pragma unroll
    for (int mi = 0; mi < MI; ++mi) {
#pragma unroll
        for (int r = 0; r < 4; ++r) {
            const int row = crow0 + mi * 16 + r;
            float bvs = HAS_BIAS ? bias[row] : 0.f;
#pragma unroll
            for (int ni = 0; ni < 4; ++ni) {
                const float v = acc[mi][ni][r] + bvs;
                const long idx = (long)bz * sC + (long)row * N + ccol + ni * 16;
                if (OUT_F32) ((float*)C)[idx] = v;
                else         ((u16*)C)[idx]   = f2bf(v);
            }
        }
    }
}

// ---------------------------------------------------------------------------
// x fp32 [b,512,1024] -> Xt bf16 [b,1024,512] (cast + transpose, 64x64 tiles,
// float4 reads / ushort4 writes)
// ---------------------------------------------------------------------------
__global__ __launch_bounds__(256) void cast_transpose_x(
    const float* __restrict__ in, u16* __restrict__ out)
{
    __shared__ u16 tile[64][68];
    const int bz = blockIdx.z;
    const float* ip = in  + (long)bz * (512 * 1024);
    u16*         op = out + (long)bz * (1024 * 512);
    const int c0 = blockIdx.x * 64;
    const int r0 = blockIdx.y * 64;
    const int tx = threadIdx.x & 15;
    const int ty = threadIdx.x >> 4;
#pragma unroll
    for (int p = 0; p < 4; ++p) {
        const int row = ty + 16 * p;
        float4 v = *(const float4*)(ip + (long)(r0 + row) * 1024 + c0 + 4 * tx);
        ushort4 o;
        o.x = f2bf(v.x); o.y = f2bf(v.y); o.z = f2bf(v.z); o.w = f2bf(v.w);
        *(ushort4*)&tile[row][4 * tx] = o;
    }
    __syncthreads();
#pragma unroll
    for (int p = 0; p < 4; ++p) {
        const int orow = ty + 16 * p;
        ushort4 o;
        o.x = tile[4 * tx + 0][orow];
        o.y = tile[4 * tx + 1][orow];
        o.z = tile[4 * tx + 2][orow];
        o.w = tile[4 * tx + 3][orow];
        *(ushort4*)&op[(long)(c0 + orow) * 512 + r0 + 4 * tx] = o;
    }
}

// ---------------------------------------------------------------------------
// bf16 64x64 tiled transpose, per-batch [512,1024] -> [1024,512], ushort4 I/O
// ---------------------------------------------------------------------------
__global__ __launch_bounds__(256) void transpose_rc(
    const u16* __restrict__ in, u16* __restrict__ out, long sIn, long sOut)
{
    __shared__ u16 tile[64][68];
    const int bz = blockIdx.z;
    const u16* ip = in  + (long)bz * sIn;
    u16*       op = out + (long)bz * sOut;
    const int c0 = blockIdx.x * 64;
    const int r0 = blockIdx.y * 64;
    const int tx = threadIdx.x & 15;
    const int ty = threadIdx.x >> 4;
#pragma unroll
    for (int p = 0; p < 4; ++p) {
        const int row = ty + 16 * p;
        ushort4 v = *(const ushort4*)(ip + (long)(r0 + row) * 1024 + c0 + 4 * tx);
        *(ushort4*)&tile[row][4 * tx] = v;
    }
    __syncthreads();
#pragma unroll
    for (int p = 0; p < 4; ++p) {
        const int orow = ty + 16 * p;
        ushort4 o;
        o.x = tile[4 * tx + 0][orow];
        o.y = tile[4 * tx + 1][orow];
        o.z = tile[4 * tx + 2][orow];
        o.w = tile[4 * tx + 3][orow];
        *(ushort4*)&op[(long)(c0 + orow) * 512 + r0 + 4 * tx] = o;
    }
}

// ---------------------------------------------------------------------------
// weights: wA/wB/wV -> Wcat bf16 [1536,512]; wR -> wRb bf16 [512,512];
// bA/bB/bV -> bcat fp32 [1536]
// ---------------------------------------------------------------------------
__global__ __launch_bounds__(256) void cast_weights(
    const float* __restrict__ wA, const float* __restrict__ wB,
    const float* __restrict__ wV, const float* __restrict__ wR,
    const float* __restrict__ bA, const float* __restrict__ bB,
    const float* __restrict__ bV,
    u16* __restrict__ Wcat, u16* __restrict__ wRb, float* __restrict__ bcat)
{
    const int tid = blockIdx.x * 256 + threadIdx.x;
    if (tid < 786432) {
        const int wsel = tid >> 18, off = tid & 262143;
        const float* src = (wsel == 0) ? wA : (wsel == 1) ? wB : wV;
        Wcat[tid] = f2bf(src[off]);
    } else if (tid < 1048576) {
        wRb[tid - 786432] = f2bf(wR[tid - 786432]);
    } else if (tid < 1048576 + 1536) {
        const int j = tid - 1048576;
        bcat[j] = (j < 512) ? bA[j] : (j < 1024) ? bB[j - 512] : bV[j - 1024];
    }
}

// ---------------------------------------------------------------------------
// Row softmax (in place, bf16) over rows 512..1535 of each batch's [1536,1024] Y
// ---------------------------------------------------------------------------
__global__ __launch_bounds__(256) void softmax_rows(u16* __restrict__ Y)
{
    u16* row = Y + (long)blockIdx.y * (1536 * 1024) + (long)(512 + blockIdx.x) * 1024;
    const int t = threadIdx.x;
    ushort4 u = ((const ushort4*)row)[t];
    float v0 = bf2f(u.x), v1 = bf2f(u.y), v2 = bf2f(u.z), v3 = bf2f(u.w);

    float m = fmaxf(fmaxf(v0, v1), fmaxf(v2, v3));
#pragma unroll
    for (int off = 32; off > 0; off >>= 1) m = fmaxf(m, __shfl_down(m, off));

    __shared__ float smax[4];
    __shared__ float ssum[4];
    const int w = t >> 6, lane = t & 63;
    if (lane == 0) smax[w] = m;
    __syncthreads();
    m = fmaxf(fmaxf(smax[0], smax[1]), fmaxf(smax[2], smax[3]));

    float e0 = __expf(v0 - m), e1 = __expf(v1 - m);
    float e2 = __expf(v2 - m), e3 = __expf(v3 - m);
    float s = e0 + e1 + e2 + e3;
#pragma unroll
    for (int off = 32; off > 0; off >>= 1) s += __shfl_down(s, off);
    if (lane == 0) ssum[w] = s;
    __syncthreads();
    const float inv = 1.0f / (ssum[0] + ssum[1] + ssum[2] + ssum[3]);

    ushort4 o;
    o.x = f2bf(e0 * inv); o.y = f2bf(e1 * inv);
    o.z = f2bf(e2 * inv); o.w = f2bf(e3 * inv);
    ((ushort4*)row)[t] = o;
}

// ---------------------------------------------------------------------------
extern "C" void kernel_launch(void* const* d_in, const int* in_sizes, int n_in,
                              void* d_out, int out_size, void* d_ws, size_t ws_size,
                              hipStream_t stream)
{
    (void)in_sizes; (void)n_in; (void)out_size; (void)ws_size;
    const float* x  = (const float*)d_in[0];
    const float* wA = (const float*)d_in[1];
    const float* bA = (const float*)d_in[2];
    const float* wB = (const float*)d_in[3];
    const float* bB = (const float*)d_in[4];
    const float* wV = (const float*)d_in[5];
    const float* bV = (const float*)d_in[6];
    const float* wR = (const float*)d_in[7];
    const float* bR = (const float*)d_in[8];
    float* out = (float*)d_out;

    const int B = 32;
    const long sY = (long)1536 * 1024;   // per-batch Y stride (bf16 elems)

    // workspace carve-up (~114 MB)
    char* p = (char*)d_ws;
    u16*   Y    = (u16*)p;   p += (long)B * sY * 2;          // 96 MB  [A;Bm;Vm]
    u16*   Gt   = (u16*)p;   p += (long)B * 512 * 512 * 2;   // 16 MB  G^T [d,c]
    u16*   Wcat = (u16*)p;   p += (long)1536 * 512 * 2;      // 1.5 MB
    u16*   wRb  = (u16*)p;   p += (long)512 * 512 * 2;       // 0.5 MB
    float* bcat = (float*)p; p += 1536 * 4;

    // Xt (bf16 [b,1024,512], 32 MB) lives in d_out — dead before GEMM6 writes out
    u16* Xt = (u16*)d_out;
    // After GEMM3: Vt reuses Y's A-region; G2 reuses Y's Bm-region
    u16* Vt = Y;                        // [1024,512] per batch, stride sY
    u16* G2 = Y + (long)512 * 1024;     // [512,512]  per batch, stride sY

    // 0. casts
    cast_transpose_x<<<dim3(16, 8, B), 256, 0, stream>>>(x, Xt);
    cast_weights<<<dim3(4103), 256, 0, stream>>>(wA, wB, wV, wR, bA, bB, bV,
                                                 Wcat, wRb, bcat);

    // 1. Y[b] = Wcat * X[b] + bcat   (NT: A=Wcat[1536,512], B=Xt[1024,512])
    gemm_nt<128, true, false><<<dim3(8, 12, B), 256, 0, stream>>>(
        Wcat, Xt, Y, bcat, 1536, 1024, 512, 0, (long)1024 * 512, sY);

    // 2. softmax over spatial for Bm and Vm rows (in place)
    softmax_rows<<<dim3(1024, B), 256, 0, stream>>>(Y);

    // 3. Gt[b][d,c] = sum_n attnM[d,n] * A[c,n]   (NT, K=1024; TM=64 -> 1024 blocks)
    gemm_nt<64, false, false><<<dim3(4, 8, B), 256, 0, stream>>>(
        Y + (long)512 * 1024, Y, Gt, nullptr, 512, 512, 1024,
        sY, sY, (long)512 * 512);

    // 4. Vt[b] = attnV[b]^T  (A-region of Y is dead now)
    transpose_rc<<<dim3(16, 8, B), 256, 0, stream>>>(
        Y + (long)1024 * 1024, Vt, sY, sY);

    // 5. G2[b][o,d] = sum_c wR[o,c] * Gt[d,c]   (NT, K=512; TM=64 -> 1024 blocks)
    gemm_nt<64, false, false><<<dim3(4, 8, B), 256, 0, stream>>>(
        wRb, Gt, G2, nullptr, 512, 512, 512, 0, (long)512 * 512, sY);

    // 6. out[b][o,n] = sum_d G2[o,d] * Vt[n,d] + bR[o]   (NT, K=512, fp32 out;
    //    TM=64 -> 2048 blocks)
    gemm_nt<64, true, true><<<dim3(8, 8, B), 256, 0, stream>>>(
        G2, Vt, out, bR, 512, 1024, 512, sY, sY, (long)512 * 1024);
}

// Round 5
// 306.857 us; speedup vs baseline: 1.0921x; 1.0921x over previous
//
#include <hip/hip_runtime.h>
#include <stdint.h>

typedef unsigned short u16;
typedef __bf16  bf16x8 __attribute__((ext_vector_type(8)));
typedef float   f32x4  __attribute__((ext_vector_type(4)));

__device__ __forceinline__ u16 f2bf(float f) {
    union { float f; unsigned u; } c; c.f = f;
    unsigned r = c.u + 0x7fffu + ((c.u >> 16) & 1u);   // RNE, finite inputs
    return (u16)(r >> 16);
}
__device__ __forceinline__ float bf2f(u16 b) {
    union { unsigned u; float f; } c; c.u = ((unsigned)b) << 16; return c.f;
}

// async 16B global->LDS. Generic LDS ptr: low 32 bits are the LDS offset on gfx9+.
__device__ __forceinline__ void g2l16(const u16* g, u16* l) {
    __builtin_amdgcn_global_load_lds(
        (__attribute__((address_space(1))) void*)(uintptr_t)g,
        (__attribute__((address_space(3))) void*)(uint32_t)(uintptr_t)l,
        16, 0, 0);
}

// ---------------------------------------------------------------------------
// NT GEMM core (bf16 in, fp32 acc): C[m,n] = sum_k A[m,k]*B[n,k]
//   (+ bias[m]) (+ wRbA[m]*svec[n] rank-1 term if EPI).
// A,B row-major bf16, ld == K. Tile TM x 128, BK=64, 256 thr = 4 waves (2x2).
// LDS XOR-swizzle: physical 16B chunk = logical ^ (row&7) -> conflict-free.
// ---------------------------------------------------------------------------
template <int TM, bool HAS_BIAS, bool OUT_F32, bool EPI>
__device__ __forceinline__ void gemm_core(
    const u16* __restrict__ Ab, const u16* __restrict__ Bb, void* __restrict__ C,
    const float* __restrict__ bias, int N, int K, long cbase, int m0, int n0,
    const float* __restrict__ svec, const float* __restrict__ wRbA)
{
    constexpr int MI = TM / 32;
    constexpr int NA = TM / 32;
    __shared__ __align__(16) u16 As[TM * 64];
    __shared__ __align__(16) u16 Bs[128 * 64];

    const int t = threadIdx.x;
    const int w = t >> 6, lane = t & 63;
    const int wr = w >> 1, wc = w & 1;

    f32x4 acc[MI][4];
    const f32x4 zero = {0.f, 0.f, 0.f, 0.f};
#pragma unroll
    for (int i = 0; i < MI; ++i)
#pragma unroll
        for (int j = 0; j < 4; ++j) acc[i][j] = zero;

    int  aslot[NA]; long aoff[NA];
#pragma unroll
    for (int i = 0; i < NA; ++i) {
        const int s   = i * 256 + t;
        const int row = s >> 3;
        const int col = ((s & 7) ^ (row & 7)) * 8;
        aslot[i] = s * 8;
        aoff[i]  = (long)(m0 + row) * K + col;
    }
    int  bslot[4]; long boff[4];
#pragma unroll
    for (int i = 0; i < 4; ++i) {
        const int s   = i * 256 + t;
        const int row = s >> 3;
        const int col = ((s & 7) ^ (row & 7)) * 8;
        bslot[i] = s * 8;
        boff[i]  = (long)(n0 + row) * K + col;
    }

    const int fr = lane & 15;
    const int q  = lane >> 4;
    const int o0 = ((q ^ (fr & 7)) * 8);   // kh=0; kh=1 is o0 ^ 32
    const u16* fa = &As[(wr * (TM / 2) + fr) * 64];
    const u16* fb = &Bs[(wc * 64 + fr) * 64];

    for (int k0 = 0; k0 < K; k0 += 64) {
#pragma unroll
        for (int i = 0; i < NA; ++i) g2l16(Ab + aoff[i] + k0, &As[aslot[i]]);
#pragma unroll
        for (int i = 0; i < 4; ++i)  g2l16(Bb + boff[i] + k0, &Bs[bslot[i]]);
        __syncthreads();

#pragma unroll
        for (int kh = 0; kh < 2; ++kh) {
            const int o = o0 ^ (kh * 32);
            bf16x8 af[MI], bv[4];
#pragma unroll
            for (int mi = 0; mi < MI; ++mi) af[mi] = *(const bf16x8*)(fa + mi * 1024 + o);
#pragma unroll
            for (int ni = 0; ni < 4; ++ni)  bv[ni] = *(const bf16x8*)(fb + ni * 1024 + o);
#pragma unroll
            for (int mi = 0; mi < MI; ++mi)
#pragma unroll
                for (int ni = 0; ni < 4; ++ni)
                    acc[mi][ni] = __builtin_amdgcn_mfma_f32_16x16x32_bf16(
                        af[mi], bv[ni], acc[mi][ni], 0, 0, 0);
        }
        __syncthreads();
    }

    // C/D layout (m89-verified): col = lane&15, row = (lane>>4)*4 + reg
    const int ccol  = n0 + wc * 64 + fr;
    const int crow0 = m0 + wr * (TM / 2) + (lane >> 4) * 4;
    float se[4];
    if (EPI) {
#pragma unroll
        for (int ni = 0; ni < 4; ++ni) se[ni] = svec[ccol + ni * 16];
    }
#pragma unroll
    for (int mi = 0; mi < MI; ++mi) {
#pragma unroll
        for (int r = 0; r < 4; ++r) {
            const int row = crow0 + mi * 16 + r;
            float add = HAS_BIAS ? bias[row] : 0.f;
            float rk  = EPI ? wRbA[row] : 0.f;
#pragma unroll
            for (int ni = 0; ni < 4; ++ni) {
                float v = acc[mi][ni][r] + add;
                if (EPI) v += rk * se[ni];
                const long idx = cbase + (long)row * N + ccol + ni * 16;
                if (OUT_F32) ((float*)C)[idx] = v;
                else         ((u16*)C)[idx]   = f2bf(v);
            }
        }
    }
}

// 3D-grid variant (GEMM1, M1): blockIdx = (n-blk, m-blk, batch)
template <int TM, bool HAS_BIAS, bool OUT_F32>
__global__ __launch_bounds__(256) void gemm_nt(
    const u16* __restrict__ A, const u16* __restrict__ B, void* __restrict__ C,
    const float* __restrict__ bias, int N, int K, long sA, long sB, long sC)
{
    const int bz = blockIdx.z;
    gemm_core<TM, HAS_BIAS, OUT_F32, false>(
        A + (long)bz * sA, B + (long)bz * sB, C, bias, N, K,
        (long)bz * sC, blockIdx.y * TM, blockIdx.x * 128, nullptr, nullptr);
}

// 1D-grid XCD-swizzled variant: blk&7 selects XCD (round-robin dispatch
// heuristic); all bpb blocks of one batch land on one XCD so the per-batch
// working set (~2-3 MB) stays in that XCD's 4 MB L2.
template <int TM, bool HAS_BIAS, bool OUT_F32, bool EPI>
__global__ __launch_bounds__(256) void gemm_nt_swz(
    const u16* __restrict__ A, const u16* __restrict__ B, void* __restrict__ C,
    const float* __restrict__ bias, int N, int K, long sA, long sB, long sC,
    int bxn, int bpb, const float* __restrict__ s_all,
    const float* __restrict__ wRbA)
{
    const int blk  = blockIdx.x;
    const int xcd  = blk & 7;
    const int slot = blk >> 3;
    const int b    = xcd + 8 * (slot / bpb);
    const int wi   = slot % bpb;
    const int bx   = wi % bxn;
    const int by   = wi / bxn;
    gemm_core<TM, HAS_BIAS, OUT_F32, EPI>(
        A + (long)b * sA, B + (long)b * sB, C, bias, N, K,
        (long)b * sC, by * TM, bx * 128,
        EPI ? s_all + (long)b * 1024 : nullptr, wRbA);
}

// ---------------------------------------------------------------------------
// x fp32 [b,512,1024] -> Xt bf16 [b,1024,512] (cast + transpose, 64x64 tiles)
// ---------------------------------------------------------------------------
__global__ __launch_bounds__(256) void cast_transpose_x(
    const float* __restrict__ in, u16* __restrict__ out)
{
    __shared__ u16 tile[64][68];
    const int bz = blockIdx.z;
    const float* ip = in  + (long)bz * (512 * 1024);
    u16*         op = out + (long)bz * (1024 * 512);
    const int c0 = blockIdx.x * 64;
    const int r0 = blockIdx.y * 64;
    const int tx = threadIdx.x & 15;
    const int ty = threadIdx.x >> 4;
#pragma unroll
    for (int p = 0; p < 4; ++p) {
        const int row = ty + 16 * p;
        float4 v = *(const float4*)(ip + (long)(r0 + row) * 1024 + c0 + 4 * tx);
        ushort4 o;
        o.x = f2bf(v.x); o.y = f2bf(v.y); o.z = f2bf(v.z); o.w = f2bf(v.w);
        *(ushort4*)&tile[row][4 * tx] = o;
    }
    __syncthreads();
#pragma unroll
    for (int p = 0; p < 4; ++p) {
        const int orow = ty + 16 * p;
        ushort4 o;
        o.x = tile[4 * tx + 0][orow];
        o.y = tile[4 * tx + 1][orow];
        o.z = tile[4 * tx + 2][orow];
        o.w = tile[4 * tx + 3][orow];
        *(ushort4*)&op[(long)(c0 + orow) * 512 + r0 + 4 * tx] = o;
    }
}

// ---------------------------------------------------------------------------
// attnV [d,n] -> Vt [n,d] per batch, PLUS column-sum s[b,n] += sum_d attnV[d,n]
// (s must be pre-zeroed). in rows stride 1024, out rows stride 512.
// ---------------------------------------------------------------------------
__global__ __launch_bounds__(256) void transpose_colsum(
    const u16* __restrict__ in, u16* __restrict__ out, float* __restrict__ s,
    long sIn, long sOut)
{
    __shared__ u16 tile[64][68];
    const int bz = blockIdx.z;
    const u16* ip = in  + (long)bz * sIn;
    u16*       op = out + (long)bz * sOut;
    const int c0 = blockIdx.x * 64;   // n
    const int r0 = blockIdx.y * 64;   // d
    const int t  = threadIdx.x;
    const int tx = t & 15;
    const int ty = t >> 4;
#pragma unroll
    for (int p = 0; p < 4; ++p) {
        const int row = ty + 16 * p;
        ushort4 v = *(const ushort4*)(ip + (long)(r0 + row) * 1024 + c0 + 4 * tx);
        *(ushort4*)&tile[row][4 * tx] = v;
    }
    __syncthreads();
#pragma unroll
    for (int p = 0; p < 4; ++p) {
        const int orow = ty + 16 * p;
        ushort4 o;
        o.x = tile[4 * tx + 0][orow];
        o.y = tile[4 * tx + 1][orow];
        o.z = tile[4 * tx + 2][orow];
        o.w = tile[4 * tx + 3][orow];
        *(ushort4*)&op[(long)(c0 + orow) * 512 + r0 + 4 * tx] = o;
    }
    if (t < 64) {
        float a = 0.f;
#pragma unroll 8
        for (int d = 0; d < 64; ++d) a += bf2f(tile[d][t]);
        atomicAdd(&s[(long)bz * 1024 + c0 + t], a);
    }
}

// ---------------------------------------------------------------------------
// weights: wB/wV -> Wcat rows 512..1535 (bf16); wR -> wRb; wA -> wAtb (bf16,
// transposed); biases -> bcat fp32 [1536] with rows 0..511 = 0 (A' has no
// bias; it's folded into the rank-1 epilogue term).
// ---------------------------------------------------------------------------
__global__ __launch_bounds__(256) void cast_weights(
    const float* __restrict__ wA, const float* __restrict__ wB,
    const float* __restrict__ wV, const float* __restrict__ wR,
    const float* __restrict__ bB, const float* __restrict__ bV,
    u16* __restrict__ Wcat, u16* __restrict__ wRb, u16* __restrict__ wAtb,
    float* __restrict__ bcat)
{
    const int tid = blockIdx.x * 256 + threadIdx.x;
    if (tid < 262144) {
        Wcat[262144 + tid] = f2bf(wB[tid]);                    // rows 512..1023
    } else if (tid < 524288) {
        Wcat[262144 + tid] = f2bf(wV[tid - 262144]);           // rows 1024..1535
    } else if (tid < 786432) {
        wRb[tid - 524288] = f2bf(wR[tid - 524288]);
    } else if (tid < 1048576) {
        const int i = tid - 786432;                            // i = c*512 + cin
        wAtb[(i & 511) * 512 + (i >> 9)] = f2bf(wA[i]);        // wA^T
    } else if (tid < 1048576 + 1536) {
        const int j = tid - 1048576;
        bcat[j] = (j < 512) ? 0.f : (j < 1024) ? bB[j - 512] : bV[j - 1024];
    }
}

// wRbA[o] = sum_c wR[o,c]*bA[c], fp32. One wave per o, 4 waves/block.
__global__ __launch_bounds__(256) void compute_wrba(
    const float* __restrict__ wR, const float* __restrict__ bA,
    float* __restrict__ wRbA)
{
    const int o    = blockIdx.x * 4 + (threadIdx.x >> 6);
    const int lane = threadIdx.x & 63;
    float a = 0.f;
#pragma unroll
    for (int c = lane; c < 512; c += 64) a += wR[o * 512 + c] * bA[c];
#pragma unroll
    for (int off = 32; off > 0; off >>= 1) a += __shfl_down(a, off);
    if (lane == 0) wRbA[o] = a;
}

// ---------------------------------------------------------------------------
// Row softmax (in place, bf16) over rows 512..1535 of each batch's [1536,1024] Y
// ---------------------------------------------------------------------------
__global__ __launch_bounds__(256) void softmax_rows(u16* __restrict__ Y)
{
    u16* row = Y + (long)blockIdx.y * (1536 * 1024) + (long)(512 + blockIdx.x) * 1024;
    const int t = threadIdx.x;
    ushort4 u = ((const ushort4*)row)[t];
    float v0 = bf2f(u.x), v1 = bf2f(u.y), v2 = bf2f(u.z), v3 = bf2f(u.w);

    float m = fmaxf(fmaxf(v0, v1), fmaxf(v2, v3));
#pragma unroll
    for (int off = 32; off > 0; off >>= 1) m = fmaxf(m, __shfl_down(m, off));

    __shared__ float smax[4];
    __shared__ float ssum[4];
    const int w = t >> 6, lane = t & 63;
    if (lane == 0) smax[w] = m;
    __syncthreads();
    m = fmaxf(fmaxf(smax[0], smax[1]), fmaxf(smax[2], smax[3]));

    float e0 = __expf(v0 - m), e1 = __expf(v1 - m);
    float e2 = __expf(v2 - m), e3 = __expf(v3 - m);
    float s = e0 + e1 + e2 + e3;
#pragma unroll
    for (int off = 32; off > 0; off >>= 1) s += __shfl_down(s, off);
    if (lane == 0) ssum[w] = s;
    __syncthreads();
    const float inv = 1.0f / (ssum[0] + ssum[1] + ssum[2] + ssum[3]);

    ushort4 o;
    o.x = f2bf(e0 * inv); o.y = f2bf(e1 * inv);
    o.z = f2bf(e2 * inv); o.w = f2bf(e3 * inv);
    ((ushort4*)row)[t] = o;
}

// ---------------------------------------------------------------------------
extern "C" void kernel_launch(void* const* d_in, const int* in_sizes, int n_in,
                              void* d_out, int out_size, void* d_ws, size_t ws_size,
                              hipStream_t stream)
{
    (void)in_sizes; (void)n_in; (void)out_size; (void)ws_size;
    const float* x  = (const float*)d_in[0];
    const float* wA = (const float*)d_in[1];
    const float* bA = (const float*)d_in[2];
    const float* wB = (const float*)d_in[3];
    const float* bB = (const float*)d_in[4];
    const float* wV = (const float*)d_in[5];
    const float* bV = (const float*)d_in[6];
    const float* wR = (const float*)d_in[7];
    const float* bR = (const float*)d_in[8];
    float* out = (float*)d_out;

    const int B = 32;
    const long sY = (long)1536 * 1024;   // per-batch Y stride (bf16 elems)

    // workspace carve-up (~115 MB)
    char* p = (char*)d_ws;
    u16*   Y    = (u16*)p;   p += (long)B * sY * 2;          // 96 MB  [A';Bm;Vm]
    u16*   H    = (u16*)p;   p += (long)B * 512 * 512 * 2;   // 16 MB  H [o,d]
    u16*   Wcat = (u16*)p;   p += (long)1536 * 512 * 2;      // [M1;wB;wV]
    u16*   wRb  = (u16*)p;   p += (long)512 * 512 * 2;
    u16*   wAtb = (u16*)p;   p += (long)512 * 512 * 2;       // wA^T bf16
    float* bcat = (float*)p; p += 1536 * 4;
    float* svec = (float*)p; p += (long)B * 1024 * 4;        // colsum of attnV
    float* wRbA = (float*)p; p += 512 * 4;

    // Xt (bf16 [b,1024,512], 33.5 MB) lives in d_out — dead before final GEMM
    u16* Xt = (u16*)d_out;
    // Vt reuses Y's A'-region after the H-GEMM consumed A'
    u16* Vt = Y;                        // [1024,512] per batch, stride sY

    // 0. casts + tiny precomputes
    cast_transpose_x<<<dim3(16, 8, B), 256, 0, stream>>>(x, Xt);
    cast_weights<<<dim3(4103), 256, 0, stream>>>(wA, wB, wV, wR, bB, bV,
                                                 Wcat, wRb, wAtb, bcat);
    compute_wrba<<<dim3(128), 256, 0, stream>>>(wR, bA, wRbA);
    hipMemsetAsync(svec, 0, (long)B * 1024 * 4, stream);

    // 1. M1 = wR*wA -> Wcat rows 0..511   (NT: A=wRb[512,512], B=wAtb[512,512])
    gemm_nt<128, false, false><<<dim3(4, 4, 1), 256, 0, stream>>>(
        wRb, wAtb, Wcat, nullptr, 512, 512, 0, 0, 0);

    // 2. Y[b] = Wcat * X[b] + bcat   (rows 0..511 = A' = M1*X, no bias)
    gemm_nt<128, true, false><<<dim3(8, 12, B), 256, 0, stream>>>(
        Wcat, Xt, Y, bcat, 1024, 512, 0, (long)1024 * 512, sY);

    // 3. softmax over spatial for Bm and Vm rows (in place)
    softmax_rows<<<dim3(1024, B), 256, 0, stream>>>(Y);

    // 4. H[b][o,d] = sum_n A'[o,n]*attnM[d,n]   (NT, K=1024; XCD-swizzled)
    gemm_nt_swz<128, false, false, false><<<dim3(512), 256, 0, stream>>>(
        Y, Y + (long)512 * 1024, H, nullptr, 512, 1024,
        sY, sY, (long)512 * 512, 4, 16, nullptr, nullptr);

    // 5. Vt[b] = attnV[b]^T + colsum s   (A'-region of Y is dead now)
    transpose_colsum<<<dim3(16, 8, B), 256, 0, stream>>>(
        Y + (long)1024 * 1024, Vt, svec, sY, sY);

    // 6. out[b][o,n] = sum_d H[o,d]*Vt[n,d] + wRbA[o]*s[n] + bR[o]  (fp32 out)
    gemm_nt_swz<128, true, true, true><<<dim3(1024), 256, 0, stream>>>(
        H, Vt, out, bR, 1024, 512, (long)512 * 512, sY, (long)512 * 1024,
        8, 32, svec, wRbA);
}